// Round 4
// baseline (49.304 us; speedup 1.0000x reference)
//
#include <hip/hip_runtime.h>

// GAT block, B=8, N=2048, F=64.
// out = softmax(mask_adj(relu(s1_i+s2_j+ab1))) @ h1  +  h2
//   h1 = x@W1^T + b1 ; h2 = x@W2^T + b2 (identity-mask layer is exactly h2)
// e = relu(...) in [0,~5] => exp safe, no max subtraction needed.

#define DEVI __device__ __forceinline__

typedef __attribute__((ext_vector_type(8))) short short8;
typedef __attribute__((ext_vector_type(4))) float floatx4;

DEVI unsigned short f2bf(float x) {
    unsigned u = __builtin_bit_cast(unsigned, x);
    unsigned r = u + 0x7FFFu + ((u >> 16) & 1u);
    return (unsigned short)(r >> 16);
}

DEVI short8 pack8(const float* v) {
    short8 r;
#pragma unroll
    for (int i = 0; i < 8; ++i) r[i] = (short)f2bf(v[i]);
    return r;
}

DEVI unsigned cvt_pk_bf16(float lo, float hi) {
    unsigned r;
    asm("v_cvt_pk_bf16_f32 %0, %1, %2" : "=v"(r) : "v"(lo), "v"(hi));
    return r;
}

// ---------------- Kernel 1: h1 (transposed, bf16), t1 = s1+ab1, s2 ----------
__global__ __launch_bounds__(256) void k_prep(
    const float* __restrict__ x, const float* __restrict__ W1,
    const float* __restrict__ b1, const float* __restrict__ a1,
    const float* __restrict__ ab1,
    unsigned short* __restrict__ hT1,   // [8][64][2048] bf16
    float* __restrict__ t1,             // [8*2048]
    float* __restrict__ s2a)            // [8*2048]
{
    __shared__ __align__(16) unsigned short hstage[64][72];
    const int tid = threadIdx.x;
    const int w = tid >> 6, lane = tid & 63;
    const int g = lane >> 4, r15 = lane & 15;
    const int blockRow = blockIdx.x * 64;
    const int rowbase = blockRow + w * 16;

    float xa[8], xb[8];
    const float* xrow = x + (long)(rowbase + r15) * 64;
#pragma unroll
    for (int e = 0; e < 8; ++e) { xa[e] = xrow[g * 8 + e]; xb[e] = xrow[32 + g * 8 + e]; }
    short8 A0 = pack8(xa), A1 = pack8(xb);

    floatx4 acc[4];
#pragma unroll
    for (int nt = 0; nt < 4; ++nt) {
        float wa[8], wb[8];
        const float* wrow = W1 + (nt * 16 + r15) * 64;
#pragma unroll
        for (int e = 0; e < 8; ++e) { wa[e] = wrow[g * 8 + e]; wb[e] = wrow[32 + g * 8 + e]; }
        short8 B0 = pack8(wa), B1 = pack8(wb);
        floatx4 c = {0.f, 0.f, 0.f, 0.f};
        c = __builtin_amdgcn_mfma_f32_16x16x32_bf16(A0, B0, c, 0, 0, 0);
        c = __builtin_amdgcn_mfma_f32_16x16x32_bf16(A1, B1, c, 0, 0, 0);
        float bias = b1[nt * 16 + r15];
#pragma unroll
        for (int q = 0; q < 4; ++q) c[q] += bias;
        acc[nt] = c;
    }

    float a1lo[4], a1hi[4];
#pragma unroll
    for (int nt = 0; nt < 4; ++nt) {
        a1lo[nt] = a1[nt * 16 + r15];
        a1hi[nt] = a1[64 + nt * 16 + r15];
    }
    float s1q[4], s2q[4];
#pragma unroll
    for (int q = 0; q < 4; ++q) {
        float s1 = 0.f, s2 = 0.f;
#pragma unroll
        for (int nt = 0; nt < 4; ++nt) { s1 += acc[nt][q] * a1lo[nt]; s2 += acc[nt][q] * a1hi[nt]; }
#pragma unroll
        for (int m = 1; m < 16; m <<= 1) { s1 += __shfl_xor(s1, m); s2 += __shfl_xor(s2, m); }
        s1q[q] = s1; s2q[q] = s2;
    }
    if (r15 == 0) {
        float abv = ab1[0];
#pragma unroll
        for (int q = 0; q < 4; ++q) {
            t1[rowbase + 4 * g + q] = s1q[q] + abv;
            s2a[rowbase + 4 * g + q] = s2q[q];
        }
    }

#pragma unroll
    for (int nt = 0; nt < 4; ++nt)
#pragma unroll
        for (int q = 0; q < 4; ++q)
            hstage[nt * 16 + r15][w * 16 + 4 * g + q] = f2bf(acc[nt][q]);
    __syncthreads();
    {
        const int o = tid >> 2, seg = (tid & 3) * 16;
        const int bb = blockRow >> 11;
        const int ib = blockRow & 2047;
        unsigned short* dst = hT1 + ((long)(bb * 64 + o) * 2048) + ib + seg;
        uint4 v0 = *(const uint4*)&hstage[o][seg];
        uint4 v1 = *(const uint4*)&hstage[o][seg + 8];
        *(uint4*)dst = v0;
        *(uint4*)(dst + 8) = v1;
    }
}

// ---------------- Kernel 2: masked softmax @ h1 + h2 ------------------------
// grid 256 (b = bi>>5, i-tile = (bi&31)*64), block 512 = 8 waves = 2 j-teams
// of 4 waves. Team t handles j-chunks [16t,16t+16). NO barriers in the k-loop:
// B-fragments come straight from L1/L2 (h1T per batch = 256 KB, resident);
// plds is per-wave. Teams' partials combined once at the end.
__global__ __launch_bounds__(512) void k_attn(
    const float* __restrict__ x, const int* __restrict__ adj,
    const float* __restrict__ W2, const float* __restrict__ b2,
    const unsigned short* __restrict__ hT1,
    const float* __restrict__ t1, const float* __restrict__ s2a,
    float* __restrict__ out)
{
    __shared__ __align__(16) unsigned short plds[8][16][72];  // per-wave P
    __shared__ __align__(16) float accbuf[4][16][64];         // team1 acc handoff
    __shared__ __align__(16) float h2buf[4][16][64];          // team1 h2 handoff
    __shared__ float ldenom[2][4][16];

    const int tid = threadIdx.x;
    const int w = tid >> 6, lane = tid & 63;
    const int t = w >> 2, wrow = w & 3;
    const int g = lane >> 4, r15 = lane & 15;   // g = row-subgroup / k-group, r15 = j-quad / m,n-lane
    const int bb = blockIdx.x >> 5;
    const int i0 = (blockIdx.x & 31) * 64;
    const int rowbase = i0 + wrow * 16;
    const int jbase = t * 16;                   // team's chunk range [jbase, jbase+16)

    // per-thread rows: row = rr*4 + g (rr = 0..3)
    float tr4[4];
#pragma unroll
    for (int rr = 0; rr < 4; ++rr) tr4[rr] = t1[bb * 2048 + rowbase + rr * 4 + g];
    float lpart[4];
#pragma unroll
    for (int rr = 0; rr < 4; ++rr) lpart[rr] = 0.f;
    floatx4 acc[4];
#pragma unroll
    for (int nt = 0; nt < 4; ++nt) acc[nt] = (floatx4){0.f, 0.f, 0.f, 0.f};

    const int4* adjq = (const int4*)(adj + (long)(bb * 2048 + rowbase + g) * 2048) + r15;
    const float4* s2q = (const float4*)(s2a + (long)bb * 2048) + r15;
    const unsigned short* hbase = hT1 + (long)(bb * 64 + r15) * 2048 + g * 8;

    int4 adjA[4], adjB[4];
    float4 A_s2, B_s2;
    short8 b0A[4], b1A[4], b0B[4], b1B[4];

#define LOADSET(S, c) do {                                                     \
        const int jc_ = jbase + (c);                                           \
        S##_s2 = s2q[jc_ * 16];                                                \
        _Pragma("unroll")                                                      \
        for (int rr_ = 0; rr_ < 4; ++rr_) adj##S[rr_] = adjq[rr_ * 2048 + jc_ * 16]; \
        _Pragma("unroll")                                                      \
        for (int nt_ = 0; nt_ < 4; ++nt_) {                                    \
            b0##S[nt_] = *(const short8*)(hbase + nt_ * 32768 + jc_ * 64);     \
            b1##S[nt_] = *(const short8*)(hbase + nt_ * 32768 + jc_ * 64 + 32);\
        }                                                                      \
    } while (0)

#define COMPUTE(S) do {                                                        \
        _Pragma("unroll")                                                      \
        for (int rr_ = 0; rr_ < 4; ++rr_) {                                    \
            float z0 = fmaxf(tr4[rr_] + S##_s2.x, 0.f);                        \
            float z1 = fmaxf(tr4[rr_] + S##_s2.y, 0.f);                        \
            float z2 = fmaxf(tr4[rr_] + S##_s2.z, 0.f);                        \
            float z3 = fmaxf(tr4[rr_] + S##_s2.w, 0.f);                        \
            float p0 = adj##S[rr_].x > 0 ? __expf(z0) : 0.f;                   \
            float p1 = adj##S[rr_].y > 0 ? __expf(z1) : 0.f;                   \
            float p2 = adj##S[rr_].z > 0 ? __expf(z2) : 0.f;                   \
            float p3 = adj##S[rr_].w > 0 ? __expf(z3) : 0.f;                   \
            lpart[rr_] += (p0 + p1) + (p2 + p3);                               \
            uint2 u;                                                           \
            u.x = cvt_pk_bf16(p0, p1);                                         \
            u.y = cvt_pk_bf16(p2, p3);                                         \
            *(uint2*)&plds[w][rr_ * 4 + g][r15 * 4] = u;                       \
        }                                                                      \
        short8 a0 = *(const short8*)&plds[w][r15][g * 8];                      \
        short8 a1 = *(const short8*)&plds[w][r15][32 + g * 8];                 \
        _Pragma("unroll")                                                      \
        for (int nt_ = 0; nt_ < 4; ++nt_) {                                    \
            acc[nt_] = __builtin_amdgcn_mfma_f32_16x16x32_bf16(a0, b0##S[nt_], acc[nt_], 0, 0, 0); \
            acc[nt_] = __builtin_amdgcn_mfma_f32_16x16x32_bf16(a1, b1##S[nt_], acc[nt_], 0, 0, 0); \
        }                                                                      \
    } while (0)

    LOADSET(A, 0);
    LOADSET(B, 1);
#pragma unroll 2
    for (int ith = 0; ith < 8; ++ith) {
        COMPUTE(A);
        if (ith < 7) LOADSET(A, 2 * ith + 2);
        COMPUTE(B);
        if (ith < 7) LOADSET(B, 2 * ith + 3);
    }
#undef LOADSET
#undef COMPUTE

    // denominator: reduce over j-lanes (bits 0-3 of lane)
#pragma unroll
    for (int rr = 0; rr < 4; ++rr) {
        float v = lpart[rr];
#pragma unroll
        for (int m = 1; m < 16; m <<= 1) v += __shfl_xor(v, m);
        if (r15 == 0) ldenom[t][wrow][rr * 4 + g] = v;
    }

    if (t == 1) {
        // hand off attention partials
#pragma unroll
        for (int nt = 0; nt < 4; ++nt)
#pragma unroll
            for (int q = 0; q < 4; ++q)
                accbuf[wrow][4 * g + q][nt * 16 + r15] = acc[nt][q];
        // compute h2 = x@W2^T + b2 for this wave's rows
        float xa[8], xb[8];
        const float* xrow = x + ((long)(bb * 2048 + rowbase + r15)) * 64;
#pragma unroll
        for (int e = 0; e < 8; ++e) { xa[e] = xrow[g * 8 + e]; xb[e] = xrow[32 + g * 8 + e]; }
        short8 A0 = pack8(xa), A1 = pack8(xb);
#pragma unroll
        for (int nt = 0; nt < 4; ++nt) {
            float wa[8], wb[8];
            const float* wrow2 = W2 + (nt * 16 + r15) * 64;
#pragma unroll
            for (int e = 0; e < 8; ++e) { wa[e] = wrow2[g * 8 + e]; wb[e] = wrow2[32 + g * 8 + e]; }
            short8 B0 = pack8(wa), B1 = pack8(wb);
            floatx4 c = {0.f, 0.f, 0.f, 0.f};
            c = __builtin_amdgcn_mfma_f32_16x16x32_bf16(A0, B0, c, 0, 0, 0);
            c = __builtin_amdgcn_mfma_f32_16x16x32_bf16(A1, B1, c, 0, 0, 0);
            float bias = b2[nt * 16 + r15];
#pragma unroll
            for (int q = 0; q < 4; ++q)
                h2buf[wrow][4 * g + q][nt * 16 + r15] = c[q] + bias;
        }
    }
    __syncthreads();

    if (t == 0) {
        float linv[4];
#pragma unroll
        for (int q = 0; q < 4; ++q)
            linv[q] = 1.0f / (ldenom[0][wrow][4 * g + q] + ldenom[1][wrow][4 * g + q]);
#pragma unroll
        for (int nt = 0; nt < 4; ++nt)
#pragma unroll
            for (int q = 0; q < 4; ++q) {
                float total = acc[nt][q] + accbuf[wrow][4 * g + q][nt * 16 + r15];
                float val = total * linv[q] + h2buf[wrow][4 * g + q][nt * 16 + r15];
                out[((long)(bb * 2048 + rowbase + 4 * g + q)) * 64 + nt * 16 + r15] = val;
            }
    }
}

extern "C" void kernel_launch(void* const* d_in, const int* in_sizes, int n_in,
                              void* d_out, int out_size, void* d_ws, size_t ws_size,
                              hipStream_t stream) {
    const float* x   = (const float*)d_in[0];
    const int*   adj = (const int*)d_in[1];
    // d_in[2] identity: unused (mask == I exactly -> layer2 == h2)
    const float* W1  = (const float*)d_in[3];
    const float* b1  = (const float*)d_in[4];
    const float* a1  = (const float*)d_in[5];
    const float* ab1 = (const float*)d_in[6];
    const float* W2  = (const float*)d_in[7];
    const float* b2  = (const float*)d_in[8];
    // d_in[9] a2, d_in[10] ab2: unused

    unsigned short* hT1 = (unsigned short*)d_ws;                 // 2 MB
    float* t1  = (float*)((char*)d_ws + (size_t)8 * 64 * 2048 * 2);
    float* s2a = t1 + 8 * 2048;

    k_prep<<<256, 256, 0, stream>>>(x, W1, b1, a1, ab1, hT1, t1, s2a);
    k_attn<<<256, 512, 0, stream>>>(x, adj, W2, b2, hT1, t1, s2a, (float*)d_out);
}

// Round 5
// 40.011 us; speedup vs baseline: 1.2323x; 1.2323x over previous
//
#include <hip/hip_runtime.h>

// GAT block, B=8, N=2048, F=64.
// out = softmax(mask_adj(relu(s1_i+s2_j+ab1))) @ h1  +  h2
//   h1 = x@W1^T + b1 ; h2 = x@W2^T + b2 (identity-mask layer is exactly h2)
// e = relu(...) in [0,~5] => exp safe, no max subtraction needed.
// k_attn: R2 barriered-LDS structure, but raw s_barrier (lgkmcnt-only drain,
// no vmcnt(0)) + depth-3 adj prefetch ring; denominator via all-ones MFMA.

#define DEVI __device__ __forceinline__

typedef __attribute__((ext_vector_type(8))) short short8;
typedef __attribute__((ext_vector_type(4))) float floatx4;

DEVI unsigned short f2bf(float x) {
    unsigned u = __builtin_bit_cast(unsigned, x);
    unsigned r = u + 0x7FFFu + ((u >> 16) & 1u);
    return (unsigned short)(r >> 16);
}

DEVI short8 pack8(const float* v) {
    short8 r;
#pragma unroll
    for (int i = 0; i < 8; ++i) r[i] = (short)f2bf(v[i]);
    return r;
}

DEVI unsigned cvt_pk_bf16(float lo, float hi) {
    unsigned r;
    asm("v_cvt_pk_bf16_f32 %0, %1, %2" : "=v"(r) : "v"(lo), "v"(hi));
    return r;
}

// team barrier: LDS-visibility only, do NOT drain vmcnt (keeps prefetch alive)
DEVI void team_sync() {
    __builtin_amdgcn_sched_barrier(0);
    asm volatile("s_waitcnt lgkmcnt(0)" ::: "memory");
    __builtin_amdgcn_s_barrier();
    __builtin_amdgcn_sched_barrier(0);
}

// ---------------- Kernel 1: h1 (transposed, bf16), t1 = s1+ab1, s2 ----------
__global__ __launch_bounds__(256) void k_prep(
    const float* __restrict__ x, const float* __restrict__ W1,
    const float* __restrict__ b1, const float* __restrict__ a1,
    const float* __restrict__ ab1,
    unsigned short* __restrict__ hT1,   // [8][64][2048] bf16
    float* __restrict__ t1,             // [8*2048]
    float* __restrict__ s2a)            // [8*2048]
{
    __shared__ __align__(16) unsigned short hstage[64][72];
    const int tid = threadIdx.x;
    const int w = tid >> 6, lane = tid & 63;
    const int g = lane >> 4, r15 = lane & 15;
    const int blockRow = blockIdx.x * 64;
    const int rowbase = blockRow + w * 16;

    float xa[8], xb[8];
    const float* xrow = x + (long)(rowbase + r15) * 64;
#pragma unroll
    for (int e = 0; e < 8; ++e) { xa[e] = xrow[g * 8 + e]; xb[e] = xrow[32 + g * 8 + e]; }
    short8 A0 = pack8(xa), A1 = pack8(xb);

    floatx4 acc[4];
#pragma unroll
    for (int nt = 0; nt < 4; ++nt) {
        float wa[8], wb[8];
        const float* wrow = W1 + (nt * 16 + r15) * 64;
#pragma unroll
        for (int e = 0; e < 8; ++e) { wa[e] = wrow[g * 8 + e]; wb[e] = wrow[32 + g * 8 + e]; }
        short8 B0 = pack8(wa), B1 = pack8(wb);
        floatx4 c = {0.f, 0.f, 0.f, 0.f};
        c = __builtin_amdgcn_mfma_f32_16x16x32_bf16(A0, B0, c, 0, 0, 0);
        c = __builtin_amdgcn_mfma_f32_16x16x32_bf16(A1, B1, c, 0, 0, 0);
        float bias = b1[nt * 16 + r15];
#pragma unroll
        for (int q = 0; q < 4; ++q) c[q] += bias;
        acc[nt] = c;
    }

    float a1lo[4], a1hi[4];
#pragma unroll
    for (int nt = 0; nt < 4; ++nt) {
        a1lo[nt] = a1[nt * 16 + r15];
        a1hi[nt] = a1[64 + nt * 16 + r15];
    }
    float s1q[4], s2q[4];
#pragma unroll
    for (int q = 0; q < 4; ++q) {
        float s1 = 0.f, s2 = 0.f;
#pragma unroll
        for (int nt = 0; nt < 4; ++nt) { s1 += acc[nt][q] * a1lo[nt]; s2 += acc[nt][q] * a1hi[nt]; }
#pragma unroll
        for (int m = 1; m < 16; m <<= 1) { s1 += __shfl_xor(s1, m); s2 += __shfl_xor(s2, m); }
        s1q[q] = s1; s2q[q] = s2;
    }
    if (r15 == 0) {
        float abv = ab1[0];
#pragma unroll
        for (int q = 0; q < 4; ++q) {
            t1[rowbase + 4 * g + q] = s1q[q] + abv;
            s2a[rowbase + 4 * g + q] = s2q[q];
        }
    }

#pragma unroll
    for (int nt = 0; nt < 4; ++nt)
#pragma unroll
        for (int q = 0; q < 4; ++q)
            hstage[nt * 16 + r15][w * 16 + 4 * g + q] = f2bf(acc[nt][q]);
    __syncthreads();
    {
        const int o = tid >> 2, seg = (tid & 3) * 16;
        const int bb = blockRow >> 11;
        const int ib = blockRow & 2047;
        unsigned short* dst = hT1 + ((long)(bb * 64 + o) * 2048) + ib + seg;
        uint4 v0 = *(const uint4*)&hstage[o][seg];
        uint4 v1 = *(const uint4*)&hstage[o][seg + 8];
        *(uint4*)dst = v0;
        *(uint4*)(dst + 8) = v1;
    }
}

// ---------------- Kernel 2: masked softmax @ h1 + h2 ------------------------
// grid 256 (b = bi>>5, i-tile = (bi&31)*64), block 512 = 8 waves = 2 j-teams
// of 4 waves; team t = chunks [16t,16t+16). One raw s_barrier per chunk.
__global__ __launch_bounds__(512) void k_attn(
    const float* __restrict__ x, const int* __restrict__ adj,
    const float* __restrict__ W2, const float* __restrict__ b2,
    const unsigned short* __restrict__ hT1,
    const float* __restrict__ t1, const float* __restrict__ s2a,
    float* __restrict__ out)
{
    __shared__ __align__(16) unsigned short hl[2][2][64][72];  // [team][buf][f][j]
    __shared__ __align__(16) unsigned short plds[8][16][72];   // per-wave P
    __shared__ __align__(16) float accbuf[4][16][64];          // team1 acc handoff
    __shared__ __align__(16) float h2buf[4][16][64];           // team1 h2 handoff
    __shared__ float denbuf[4][16];                            // team1 denom handoff

    const int tid = threadIdx.x;
    const int w = tid >> 6, lane = tid & 63;
    const int t = w >> 2, wrow = w & 3;
    const int g = lane >> 4, r15 = lane & 15;
    const int bb = blockIdx.x >> 5;
    const int i0 = (blockIdx.x & 31) * 64;
    const int rowbase = i0 + wrow * 16;
    const int jbase = t * 16;

    // per-thread rows: row-in-tile = rr*4 + g
    float tr4[4];
#pragma unroll
    for (int rr = 0; rr < 4; ++rr) tr4[rr] = t1[bb * 2048 + rowbase + rr * 4 + g];

    floatx4 acc[4];
#pragma unroll
    for (int nt = 0; nt < 4; ++nt) acc[nt] = (floatx4){0.f, 0.f, 0.f, 0.f};
    floatx4 acc5 = {0.f, 0.f, 0.f, 0.f};   // row-sum of P (denominator)

    short8 ones;
#pragma unroll
    for (int i = 0; i < 8; ++i) ones[i] = (short)0x3F80;   // bf16 1.0

    const int4* adjq = (const int4*)(adj + (long)(bb * 2048 + rowbase + g) * 2048) + r15;
    const float4* s2q4 = (const float4*)(s2a + (long)bb * 2048) + r15;

    // hl staging: team-local 256 threads cover 64 f-rows x 64 j
    const int ttid = tid & 255;
    const int so = ttid >> 2, sseg = (ttid & 3) * 16;
    const unsigned short* hTsrc = hT1 + (long)(bb * 64 + so) * 2048 + sseg;
    unsigned short* hldst[2] = { &hl[t][0][so][sseg], &hl[t][1][so][sseg] };

    int4 adjR[4][4];      // [slot][rr]
    float4 s2R[4];
    uint4 hrg[2][2];      // [parity][half]

#define LOAD_ADJ(slot, c) do {                                                 \
        const int jc_ = jbase + (c);                                           \
        s2R[slot] = s2q4[jc_ * 16];                                            \
        _Pragma("unroll")                                                      \
        for (int rr_ = 0; rr_ < 4; ++rr_)                                      \
            adjR[slot][rr_] = adjq[rr_ * 2048 + jc_ * 16];                     \
    } while (0)

#define LOAD_HT(par, c) do {                                                   \
        const unsigned short* src_ = hTsrc + (jbase + (c)) * 64;               \
        hrg[par][0] = *(const uint4*)src_;                                     \
        hrg[par][1] = *(const uint4*)(src_ + 8);                               \
    } while (0)

#define STORE_HT(par) do {                                                     \
        *(uint4*)hldst[par] = hrg[par][0];                                     \
        *(uint4*)(hldst[par] + 8) = hrg[par][1];                               \
    } while (0)

#define COMPUTE(C, slot, buf) do {                                             \
        _Pragma("unroll")                                                      \
        for (int rr_ = 0; rr_ < 4; ++rr_) {                                    \
            float z0 = fmaxf(tr4[rr_] + s2R[slot].x, 0.f);                     \
            float z1 = fmaxf(tr4[rr_] + s2R[slot].y, 0.f);                     \
            float z2 = fmaxf(tr4[rr_] + s2R[slot].z, 0.f);                     \
            float z3 = fmaxf(tr4[rr_] + s2R[slot].w, 0.f);                     \
            float p0 = adjR[slot][rr_].x > 0 ? __expf(z0) : 0.f;               \
            float p1 = adjR[slot][rr_].y > 0 ? __expf(z1) : 0.f;               \
            float p2 = adjR[slot][rr_].z > 0 ? __expf(z2) : 0.f;               \
            float p3 = adjR[slot][rr_].w > 0 ? __expf(z3) : 0.f;               \
            uint2 u;                                                           \
            u.x = cvt_pk_bf16(p0, p1);                                         \
            u.y = cvt_pk_bf16(p2, p3);                                         \
            *(uint2*)&plds[w][rr_ * 4 + g][r15 * 4] = u;                       \
        }                                                                      \
        short8 a0 = *(const short8*)&plds[w][r15][g * 8];                      \
        short8 a1 = *(const short8*)&plds[w][r15][32 + g * 8];                 \
        _Pragma("unroll")                                                      \
        for (int nt_ = 0; nt_ < 4; ++nt_) {                                    \
            short8 b0 = *(const short8*)&hl[t][buf][nt_ * 16 + r15][g * 8];    \
            short8 b1 = *(const short8*)&hl[t][buf][nt_ * 16 + r15][32 + g * 8]; \
            acc[nt_] = __builtin_amdgcn_mfma_f32_16x16x32_bf16(a0, b0, acc[nt_], 0, 0, 0); \
            acc[nt_] = __builtin_amdgcn_mfma_f32_16x16x32_bf16(a1, b1, acc[nt_], 0, 0, 0); \
        }                                                                      \
        acc5 = __builtin_amdgcn_mfma_f32_16x16x32_bf16(a0, ones, acc5, 0, 0, 0); \
        acc5 = __builtin_amdgcn_mfma_f32_16x16x32_bf16(a1, ones, acc5, 0, 0, 0); \
    } while (0)

    // STEP(C): issue HT(C+2)->hrg[C&1], ADJ(C+3)->slot (C+3)&3;
    // store chunk C+1 (hrg[(C+1)&1]) -> hl[(C+1)&1]; compute C; sync.
#define STEP(C) do {                                                           \
        if ((C) <= 13) LOAD_HT((C) & 1, (C) + 2);                              \
        if ((C) <= 12) LOAD_ADJ(((C) + 3) & 3, (C) + 3);                       \
        if ((C) <= 14) STORE_HT(((C) + 1) & 1);                                \
        COMPUTE((C), (C) & 3, (C) & 1);                                        \
        team_sync();                                                           \
    } while (0)

    // prologue: adj chunks 0..2 in flight; hl[0] staged; hT(1) in flight
    LOAD_ADJ(0, 0);
    LOAD_ADJ(1, 1);
    LOAD_ADJ(2, 2);
    LOAD_HT(0, 0);
    STORE_HT(0);
    LOAD_HT(1, 1);
    team_sync();

    STEP(0);  STEP(1);  STEP(2);  STEP(3);
    STEP(4);  STEP(5);  STEP(6);  STEP(7);
    STEP(8);  STEP(9);  STEP(10); STEP(11);
    STEP(12); STEP(13); STEP(14); STEP(15);

#undef STEP
#undef COMPUTE
#undef STORE_HT
#undef LOAD_HT
#undef LOAD_ADJ

    if (t == 1) {
#pragma unroll
        for (int nt = 0; nt < 4; ++nt)
#pragma unroll
            for (int q = 0; q < 4; ++q)
                accbuf[wrow][4 * g + q][nt * 16 + r15] = acc[nt][q];
        if (r15 == 0) {
#pragma unroll
            for (int q = 0; q < 4; ++q) denbuf[wrow][4 * g + q] = acc5[q];
        }
        // h2 = x@W2^T + b2 for this wave's rows
        float xa[8], xb[8];
        const float* xrow = x + ((long)(bb * 2048 + rowbase + r15)) * 64;
#pragma unroll
        for (int e = 0; e < 8; ++e) { xa[e] = xrow[g * 8 + e]; xb[e] = xrow[32 + g * 8 + e]; }
        short8 A0 = pack8(xa), A1 = pack8(xb);
#pragma unroll
        for (int nt = 0; nt < 4; ++nt) {
            float wa[8], wb[8];
            const float* wrow2 = W2 + (nt * 16 + r15) * 64;
#pragma unroll
            for (int e = 0; e < 8; ++e) { wa[e] = wrow2[g * 8 + e]; wb[e] = wrow2[32 + g * 8 + e]; }
            short8 B0 = pack8(wa), B1 = pack8(wb);
            floatx4 c = {0.f, 0.f, 0.f, 0.f};
            c = __builtin_amdgcn_mfma_f32_16x16x32_bf16(A0, B0, c, 0, 0, 0);
            c = __builtin_amdgcn_mfma_f32_16x16x32_bf16(A1, B1, c, 0, 0, 0);
            float bias = b2[nt * 16 + r15];
#pragma unroll
            for (int q = 0; q < 4; ++q)
                h2buf[wrow][4 * g + q][nt * 16 + r15] = c[q] + bias;
        }
    }
    __syncthreads();

    if (t == 0) {
        float linv[4];
#pragma unroll
        for (int q = 0; q < 4; ++q)
            linv[q] = 1.0f / (acc5[q] + denbuf[wrow][4 * g + q]);
#pragma unroll
        for (int nt = 0; nt < 4; ++nt)
#pragma unroll
            for (int q = 0; q < 4; ++q) {
                float total = acc[nt][q] + accbuf[wrow][4 * g + q][nt * 16 + r15];
                float val = total * linv[q] + h2buf[wrow][4 * g + q][nt * 16 + r15];
                out[((long)(bb * 2048 + rowbase + 4 * g + q)) * 64 + nt * 16 + r15] = val;
            }
    }
}

extern "C" void kernel_launch(void* const* d_in, const int* in_sizes, int n_in,
                              void* d_out, int out_size, void* d_ws, size_t ws_size,
                              hipStream_t stream) {
    const float* x   = (const float*)d_in[0];
    const int*   adj = (const int*)d_in[1];
    // d_in[2] identity: unused (mask == I exactly -> layer2 == h2)
    const float* W1  = (const float*)d_in[3];
    const float* b1  = (const float*)d_in[4];
    const float* a1  = (const float*)d_in[5];
    const float* ab1 = (const float*)d_in[6];
    const float* W2  = (const float*)d_in[7];
    const float* b2  = (const float*)d_in[8];
    // d_in[9] a2, d_in[10] ab2: unused

    unsigned short* hT1 = (unsigned short*)d_ws;                 // 2 MB
    float* t1  = (float*)((char*)d_ws + (size_t)8 * 64 * 2048 * 2);
    float* s2a = t1 + 8 * 2048;

    k_prep<<<256, 256, 0, stream>>>(x, W1, b1, a1, ab1, hT1, t1, s2a);
    k_attn<<<256, 512, 0, stream>>>(x, adj, W2, b2, hT1, t1, s2a, (float*)d_out);
}